// Round 9
// baseline (334.885 us; speedup 1.0000x reference)
//
#include <hip/hip_runtime.h>

#define DIN  32
#define DH   64
#define DOUT 16
#define SCAN_BLK 1024   // elements per scan block; supports N <= 262144
#define NXCD 8

typedef int   i4 __attribute__((ext_vector_type(4)));
typedef float f4 __attribute__((ext_vector_type(4)));

// ------------------------------------------------------------ degree count --
__global__ void k_count_deg(const int* __restrict__ dst, int* __restrict__ deg, int E) {
    int e = blockIdx.x * blockDim.x + threadIdx.x;
    if (e < E) {
        int d = __builtin_nontemporal_load(dst + e);   // streamed once: keep out of L2
        atomicAdd(&deg[d], 1);
    }
}

// ------------------------------------------------- scan stage 1: per-block --
__global__ void k_scan1(const int* __restrict__ deg, int* __restrict__ partial,
                        int* __restrict__ blockSums, int N) {
    __shared__ int s[256];
    int tid  = threadIdx.x;
    int base = blockIdx.x * SCAN_BLK + tid * 4;
    int v0 = (base + 0 < N) ? deg[base + 0] : 0;
    int v1 = (base + 1 < N) ? deg[base + 1] : 0;
    int v2 = (base + 2 < N) ? deg[base + 2] : 0;
    int v3 = (base + 3 < N) ? deg[base + 3] : 0;
    int tot = v0 + v1 + v2 + v3;
    s[tid] = tot;
    __syncthreads();
    for (int off = 1; off < 256; off <<= 1) {
        int t = (tid >= off) ? s[tid - off] : 0;
        __syncthreads();
        s[tid] += t;
        __syncthreads();
    }
    int excl = s[tid] - tot;
    if (base + 0 < N) partial[base + 0] = excl;
    if (base + 1 < N) partial[base + 1] = excl + v0;
    if (base + 2 < N) partial[base + 2] = excl + v0 + v1;
    if (base + 3 < N) partial[base + 3] = excl + v0 + v1 + v2;
    if (tid == 255) blockSums[blockIdx.x] = s[255];
}

// ------------------------------------ scan stage 2: scan block sums (1 blk) --
__global__ void k_scan2(int* __restrict__ blockSums, int* __restrict__ blockOff, int NB) {
    __shared__ int s[256];
    int tid = threadIdx.x;
    int v = (tid < NB) ? blockSums[tid] : 0;
    s[tid] = v;
    __syncthreads();
    for (int off = 1; off < 256; off <<= 1) {
        int t = (tid >= off) ? s[tid - off] : 0;
        __syncthreads();
        s[tid] += t;
        __syncthreads();
    }
    if (tid < NB) blockOff[tid] = s[tid] - v;
}

// ------- scan stage 3: rowStart = partial+blockOff; cursor=rowStart; dinv ---
__global__ void k_scan3(const int* __restrict__ partial, const int* __restrict__ blockOff,
                        const int* __restrict__ deg, int* __restrict__ rowStart,
                        int* __restrict__ cursor, float* __restrict__ dinv, int N) {
    int i = blockIdx.x * blockDim.x + threadIdx.x;
    if (i < N) {
        int rs = partial[i] + blockOff[i / SCAN_BLK];
        rowStart[i] = rs;
        cursor[i]   = rs;
        dinv[i]     = rsqrtf((float)deg[i] + 1.0f); // +1 self-loop
    }
}

// --------------------------- CSR fill, XCD-binned to kill write amplification
// nt loads keep the 8x streamed edge list OUT of L2 so each bin's ~800KB
// edgeSrc region stays resident and lines fill before writeback.
__global__ void k_fill(const int* __restrict__ src, const int* __restrict__ dst,
                       int* __restrict__ cursor, int* __restrict__ edgeSrc,
                       int E, int N) {
    int xcd  = blockIdx.x & (NXCD - 1);
    int blk  = blockIdx.x >> 3;
    int nblk = gridDim.x >> 3;
    int lo = (int)(((long long)xcd       * N) / NXCD);
    int hi = (int)(((long long)(xcd + 1) * N) / NXCD);

    int EV = E >> 2;   // int4 groups
    bool aligned = ((E & 3) == 0);
    if (aligned) {
        const i4* d4p = (const i4*)dst;
        const i4* s4p = (const i4*)src;
        for (int v = blk * blockDim.x + threadIdx.x; v < EV; v += nblk * blockDim.x) {
            i4 d4 = __builtin_nontemporal_load(d4p + v);
            i4 s4 = __builtin_nontemporal_load(s4p + v);
            if (d4.x >= lo && d4.x < hi) { int p = atomicAdd(&cursor[d4.x], 1); edgeSrc[p] = s4.x; }
            if (d4.y >= lo && d4.y < hi) { int p = atomicAdd(&cursor[d4.y], 1); edgeSrc[p] = s4.y; }
            if (d4.z >= lo && d4.z < hi) { int p = atomicAdd(&cursor[d4.z], 1); edgeSrc[p] = s4.z; }
            if (d4.w >= lo && d4.w < hi) { int p = atomicAdd(&cursor[d4.w], 1); edgeSrc[p] = s4.w; }
        }
    } else {
        for (int e = blk * blockDim.x + threadIdx.x; e < E; e += nblk * blockDim.x) {
            int d = __builtin_nontemporal_load(dst + e);
            if (d >= lo && d < hi) {
                int sv = __builtin_nontemporal_load(src + e);
                int p = atomicAdd(&cursor[d], 1);
                edgeSrc[p] = sv;
            }
        }
    }
}

// ------------------------------------------ xg = dinv[i] * x[i,:], float4 ---
__global__ void k_xg(const f4* __restrict__ x4, const float* __restrict__ dinv,
                     f4* __restrict__ xg4, int N) {
    int t = blockIdx.x * blockDim.x + threadIdx.x;
    if (t < N * 8) {                       // 8 quads per node
        float d = dinv[t >> 3];
        f4 v = __builtin_nontemporal_load(x4 + t);   // x streamed once
        v *= d;
        xg4[t] = v;                                  // xg reused by agg1: cached
    }
}

// ---- layer-1 aggregation ONLY (no GEMM): s_i = sum_j xg_j + xg_i -----------
// wave per node. lane = es*8 + fl: es = edge slot (0..7), fl = feature quad.
// First 32 edges as ONE predicated two-stage block; rare loop for deg > 32.
// edgeSrc is streamed once -> nt loads, so xg stays hot in L2.
__global__ void k_agg1(const int* __restrict__ rowStart, const int* __restrict__ deg,
                       const int* __restrict__ edgeSrc, const float4* __restrict__ xg4,
                       float4* __restrict__ s4, int N) {
    int tid = threadIdx.x;
    int w = tid >> 6, lane = tid & 63;
    int es = lane >> 3, fl = lane & 7;
    int node = blockIdx.x * 4 + w;   // wave-uniform
    if (node >= N) return;

    int s = rowStart[node], c = deg[node];
    float4 a0 = {0,0,0,0}, a1 = {0,0,0,0}, a2 = {0,0,0,0}, a3 = {0,0,0,0};
    int j0 = 0, j1 = 0, j2 = 0, j3 = 0;
    int o0 = es, o1 = 8 + es, o2 = 16 + es, o3 = 24 + es;
    // stage 1: all index loads in flight together
    if (o0 < c) j0 = __builtin_nontemporal_load(edgeSrc + s + o0);
    if (o1 < c) j1 = __builtin_nontemporal_load(edgeSrc + s + o1);
    if (o2 < c) j2 = __builtin_nontemporal_load(edgeSrc + s + o2);
    if (o3 < c) j3 = __builtin_nontemporal_load(edgeSrc + s + o3);
    // stage 2: all payload gathers in flight together (8 edges per instr)
    if (o0 < c) a0 = xg4[(size_t)j0 * 8 + fl];
    if (o1 < c) a1 = xg4[(size_t)j1 * 8 + fl];
    if (o2 < c) a2 = xg4[(size_t)j2 * 8 + fl];
    if (o3 < c) a3 = xg4[(size_t)j3 * 8 + fl];
    // rare long tail (deg > 32)
    for (int o = 32 + es; o < c; o += 8) {
        int j = __builtin_nontemporal_load(edgeSrc + s + o);
        float4 v = xg4[(size_t)j * 8 + fl];
        a0.x += v.x; a0.y += v.y; a0.z += v.z; a0.w += v.w;
    }
    float4 A;
    A.x = (a0.x + a1.x) + (a2.x + a3.x);
    A.y = (a0.y + a1.y) + (a2.y + a3.y);
    A.z = (a0.z + a1.z) + (a2.z + a3.z);
    A.w = (a0.w + a1.w) + (a2.w + a3.w);
#pragma unroll
    for (int m = 8; m <= 32; m <<= 1) {   // fold 8 edge slots
        A.x += __shfl_xor(A.x, m);
        A.y += __shfl_xor(A.y, m);
        A.z += __shfl_xor(A.z, m);
        A.w += __shfl_xor(A.w, m);
    }
    if (es == 0) {
        float4 sl = xg4[(size_t)node * 8 + fl];   // self-loop: dinv_i * x_i
        A.x += sl.x; A.y += sl.y; A.z += sl.z; A.w += sl.w;
        s4[(size_t)node * 8 + fl] = A;            // 128B per node, 8 lanes
    }
}

// ---- dense per-node MLP: g2 = dinv*( relu(dinv*(s@W1)+b1) @ W2 ) -----------
// ONE NODE PER LANE. W1/W2/b1 addresses are wave-uniform -> scalar loads;
// s/h/g live in registers; zero LDS, zero shfl. Fully unrolled FMA chain.
__global__ void k_gemm12(const float* __restrict__ s, const float* __restrict__ dinv,
                         const float* __restrict__ b1, const float* __restrict__ W1,
                         const float* __restrict__ W2, float* __restrict__ g2, int N) {
    int node = blockIdx.x * blockDim.x + threadIdx.x;
    if (node >= N) return;

    float sv[DIN];
    const float4* s4 = (const float4*)s;
#pragma unroll
    for (int q = 0; q < 8; ++q) {
        float4 v = s4[(size_t)node * 8 + q];
        sv[4 * q + 0] = v.x; sv[4 * q + 1] = v.y;
        sv[4 * q + 2] = v.z; sv[4 * q + 3] = v.w;
    }

    float h[DH];
#pragma unroll
    for (int k = 0; k < DH; ++k) h[k] = 0.f;
#pragma unroll
    for (int d = 0; d < DIN; ++d) {
#pragma unroll
        for (int k = 0; k < DH; ++k) h[k] += sv[d] * W1[d * DH + k];
    }
    float di = dinv[node];
#pragma unroll
    for (int k = 0; k < DH; ++k) h[k] = fmaxf(di * h[k] + b1[k], 0.f);

    float g[DOUT];
#pragma unroll
    for (int k = 0; k < DOUT; ++k) g[k] = 0.f;
#pragma unroll
    for (int d = 0; d < DH; ++d) {
#pragma unroll
        for (int k = 0; k < DOUT; ++k) g[k] += h[d] * W2[d * DOUT + k];
    }

    float4* g2_4 = (float4*)g2;
#pragma unroll
    for (int q = 0; q < 4; ++q) {
        float4 r;
        r.x = di * g[4 * q + 0]; r.y = di * g[4 * q + 1];
        r.z = di * g[4 * q + 2]; r.w = di * g[4 * q + 3];
        g2_4[(size_t)node * 4 + q] = r;
    }
}

// ---- layer-2 aggregate + finalize -------------------------------------------
// wave per node. lane = es*4 + fl: es = edge slot (0..15), fl = feature quad.
__global__ void k_agg2(const int* __restrict__ rowStart, const int* __restrict__ deg,
                       const int* __restrict__ edgeSrc, const float4* __restrict__ g2_4,
                       const float* __restrict__ dinv, const float* __restrict__ b2,
                       float4* __restrict__ out4, int N) {
    int tid = threadIdx.x;
    int w = tid >> 6, lane = tid & 63;
    int es = lane >> 2, fl = lane & 3;
    int node = blockIdx.x * 4 + w;   // wave-uniform
    if (node >= N) return;

    int s = rowStart[node], c = deg[node];
    float4 a0 = {0,0,0,0}, a1 = {0,0,0,0};
    int j0 = 0, j1 = 0;
    int o0 = es, o1 = 16 + es;
    if (o0 < c) j0 = __builtin_nontemporal_load(edgeSrc + s + o0);
    if (o1 < c) j1 = __builtin_nontemporal_load(edgeSrc + s + o1);
    if (o0 < c) a0 = g2_4[(size_t)j0 * 4 + fl];
    if (o1 < c) a1 = g2_4[(size_t)j1 * 4 + fl];
    for (int o = 32 + es; o < c; o += 16) {       // rare long tail
        int j = __builtin_nontemporal_load(edgeSrc + s + o);
        float4 v = g2_4[(size_t)j * 4 + fl];
        a0.x += v.x; a0.y += v.y; a0.z += v.z; a0.w += v.w;
    }
    float4 A;
    A.x = a0.x + a1.x; A.y = a0.y + a1.y; A.z = a0.z + a1.z; A.w = a0.w + a1.w;
#pragma unroll
    for (int m = 4; m <= 32; m <<= 1) {           // fold 16 edge slots
        A.x += __shfl_xor(A.x, m);
        A.y += __shfl_xor(A.y, m);
        A.z += __shfl_xor(A.z, m);
        A.w += __shfl_xor(A.w, m);
    }
    if (es == 0) {
        float4 sl = g2_4[(size_t)node * 4 + fl];  // self-loop
        A.x += sl.x; A.y += sl.y; A.z += sl.z; A.w += sl.w;
        float d = dinv[node];
        const float4* b2_4 = (const float4*)b2;
        float4 bq = b2_4[fl], r;
        r.x = d * A.x + bq.x; r.y = d * A.y + bq.y;
        r.z = d * A.z + bq.z; r.w = d * A.w + bq.w;
        out4[(size_t)node * 4 + fl] = r;
    }
}

// ----------------------------------------------------------------------------
static inline size_t align16(size_t v) { return (v + 15) & ~(size_t)15; }

extern "C" void kernel_launch(void* const* d_in, const int* in_sizes, int n_in,
                              void* d_out, int out_size, void* d_ws, size_t ws_size,
                              hipStream_t stream) {
    const float* x  = (const float*)d_in[0];
    const int*   ei = (const int*)  d_in[1];
    const float* W1 = (const float*)d_in[2];
    const float* b1 = (const float*)d_in[3];
    const float* W2 = (const float*)d_in[4];
    const float* b2 = (const float*)d_in[5];

    int N = in_sizes[0] / DIN;
    int E = in_sizes[1] / 2;
    const int* src = ei;
    const int* dst = ei + E;
    int NB = (N + SCAN_BLK - 1) / SCAN_BLK;

    // workspace layout, 16B-aligned regions
    char* base = (char*)d_ws;
    size_t off = 0;
    int*   deg       = (int*)(base + off);   off = align16(off + (size_t)N * 4);
    int*   partial   = (int*)(base + off);   off = align16(off + (size_t)N * 4);
    int*   rowStart  = (int*)(base + off);   off = align16(off + (size_t)N * 4);
    int*   cursor    = (int*)(base + off);   off = align16(off + (size_t)N * 4);
    int*   blockSums = (int*)(base + off);   off = align16(off + 256 * 4);
    int*   blockOff  = (int*)(base + off);   off = align16(off + 256 * 4);
    float* dinv      = (float*)(base + off); off = align16(off + (size_t)N * 4);
    int*   edgeSrc   = (int*)(base + off);   off = align16(off + (size_t)E * 4);
    float* xg        = (float*)(base + off); off = align16(off + (size_t)N * DIN * 4);
    float* sagg      = (float*)(base + off); off = align16(off + (size_t)N * DIN * 4);
    float* g2        = (float*)(base + off); off = align16(off + (size_t)N * DOUT * 4);

    hipMemsetAsync(deg, 0, (size_t)N * 4, stream);

    k_count_deg<<<(E + 255) / 256, 256, 0, stream>>>(dst, deg, E);
    k_scan1<<<NB, 256, 0, stream>>>(deg, partial, blockSums, N);
    k_scan2<<<1, 256, 0, stream>>>(blockSums, blockOff, NB);
    k_scan3<<<(N + 255) / 256, 256, 0, stream>>>(partial, blockOff, deg,
                                                 rowStart, cursor, dinv, N);

    k_fill<<<NXCD * 192, 256, 0, stream>>>(src, dst, cursor, edgeSrc, E, N);

    k_xg<<<((size_t)N * 8 + 255) / 256, 256, 0, stream>>>((const f4*)x, dinv,
                                                          (f4*)xg, N);
    k_agg1<<<(N + 3) / 4, 256, 0, stream>>>(rowStart, deg, edgeSrc,
                                            (const float4*)xg, (float4*)sagg, N);
    k_gemm12<<<(N + 255) / 256, 256, 0, stream>>>(sagg, dinv, b1, W1, W2, g2, N);
    k_agg2<<<(N + 3) / 4, 256, 0, stream>>>(rowStart, deg, edgeSrc,
                                            (const float4*)g2, dinv, b2,
                                            (float4*)d_out, N);
}